// Round 1
// 524.078 us; speedup vs baseline: 1.0858x; 1.0858x over previous
//
#include <hip/hip_runtime.h>
#include <math.h>
#include <stdint.h>

#define BB 1024
#define SS 200
#define HH 128
#define NI 100000

typedef __attribute__((ext_vector_type(8))) short short8;  // 8 bf16 (4 VGPRs)
typedef __attribute__((ext_vector_type(4))) float f32x4;   // MFMA C/D

// tanh(x) = sign(x) * (1 - e^{-2|x|}) / (1 + e^{-2|x|})
__device__ __forceinline__ float fast_tanh(float x) {
    float ax = fabsf(x);
    float t = __expf(-2.0f * ax);
    float r = (1.0f - t) / (1.0f + t);
    return copysignf(r, x);
}

// Split 8 consecutive fp32 into bf16 hi + bf16 lo (truncation split; residual
// captured exactly, dropped lo*lo term ~2^-16 relative).
__device__ __forceinline__ void split8(const float* __restrict__ p,
                                       short8& hi, short8& lo) {
    const float4* p4 = reinterpret_cast<const float4*>(p);
    float4 x0 = p4[0], x1 = p4[1];
    float v[8] = {x0.x, x0.y, x0.z, x0.w, x1.x, x1.y, x1.z, x1.w};
    #pragma unroll
    for (int j = 0; j < 8; ++j) {
        unsigned u = __float_as_uint(v[j]);
        unsigned short h = (unsigned short)(u >> 16);
        hi[j] = (short)h;
        float r = v[j] - __uint_as_float(((unsigned)h) << 16);
        lo[j] = (short)(__float_as_uint(r) >> 16);
    }
}

// ---------------------------------------------------------------------------
// Prep kernel (runs once per iteration, ~5us):
//   blocks 0..511 : lm[b][k] = sum_h last[b][h] * Wr[k][h]   (bit-identical
//                   FMA order to the old per-block computation)
//   blocks 512..519: split Ur into bf16 hi/lo fragment tables, laid out so a
//                   wave's fragment load for fixed (c,n) is 64 lanes x 16B
//                   fully contiguous with identity lane->address mapping:
//                   rec = c*512 + n*64 + quad*16 + col
// ---------------------------------------------------------------------------
__global__ __launch_bounds__(256)
void rrd_prep_kernel(const float* __restrict__ lastm,   // [B,H]
                     const float* __restrict__ Wr,      // [H,H]
                     const float* __restrict__ Ur,      // [H,H]
                     float* __restrict__ lm_ws,         // [B,H]
                     short* __restrict__ ur_hi,         // [2048] short8
                     short* __restrict__ ur_lo) {       // [2048] short8
    const int blk = blockIdx.x;
    const int tid = threadIdx.x;
    if (blk < 512) {
        const int gid = blk * 256 + tid;       // 131072 = B*H outputs
        const int b = gid >> 7;
        const int k = gid & 127;
        const float4* wrow = reinterpret_cast<const float4*>(Wr + (size_t)k * HH);
        const float4* lrow = reinterpret_cast<const float4*>(lastm + (size_t)b * HH);
        float4 acc = make_float4(0.f, 0.f, 0.f, 0.f);
        #pragma unroll
        for (int i = 0; i < HH / 4; ++i) {
            float4 wv = wrow[i];
            float4 lv = lrow[i];
            acc.x = fmaf(lv.x, wv.x, acc.x);
            acc.y = fmaf(lv.y, wv.y, acc.y);
            acc.z = fmaf(lv.z, wv.z, acc.z);
            acc.w = fmaf(lv.w, wv.w, acc.w);
        }
        lm_ws[gid] = (acc.x + acc.y) + (acc.z + acc.w);
    } else {
        const int r = (blk - 512) * 256 + tid;  // 0..2047 fragment records
        const int c    = r >> 9;
        const int n    = (r >> 6) & 7;
        const int quad = (r >> 4) & 3;
        const int col  = r & 15;
        const int row = n * 16 + col;           // Ur row (output k index)
        const int k0  = c * 32 + quad * 8;      // Ur col (inner h index)
        short8 hi, lo;
        split8(Ur + (size_t)row * HH + k0, hi, lo);
        reinterpret_cast<short8*>(ur_hi)[r] = hi;
        reinterpret_cast<short8*>(ur_lo)[r] = lo;
    }
}

// ---------------------------------------------------------------------------
// Main kernel, prefab-Ur variant: B fragments are loaded (L2-hot, 64KB x2)
// instead of re-split per pass; lm loaded from workspace. All remaining math
// is verbatim from the verified kernel.
// ---------------------------------------------------------------------------
__global__ __launch_bounds__(256, 2)
void rrd_mfma_kernel_p(const float* __restrict__ allm,      // [B,S,H]
                       const int* __restrict__ item_seq,    // [B,S]
                       const unsigned char* __restrict__ mask, // [B,S]
                       const short* __restrict__ ur_hi,     // prefab frags
                       const short* __restrict__ ur_lo,
                       const float* __restrict__ lm_ws,     // [B,H]
                       const float* __restrict__ Vr,        // [1,H]
                       const float* __restrict__ Vrb,       // [1]
                       float* __restrict__ out) {           // [B,N]
    const int b = blockIdx.x;
    const int tid = threadIdx.x;
    const int lane = tid & 63;
    const int w = tid >> 6;       // wave id: rows [64w, 64w+64)
    const int col = lane & 15;    // C col / B n / A m lane index
    const int quad = lane >> 4;   // k-quad (8 k each)

    __shared__ float s_lm[HH];
    __shared__ float s_vr[HH];
    __shared__ float s_score[256];
    __shared__ float s_red[8];

    // ---- stage lm + Vr into LDS ----
    if (tid < HH) s_lm[tid] = lm_ws[(size_t)b * HH + tid];
    else          s_vr[tid - HH] = Vr[tid - HH];
    __syncthreads();   // s_lm/s_vr ready for epilogue

    const short8* uh = reinterpret_cast<const short8*>(ur_hi);
    const short8* ul = reinterpret_cast<const short8*>(ur_lo);

    // ---- MFMA main: am[s,k] = A[s,:] . Ur[k,:], split-bf16 3-term ----
    // 2 passes x 2 m-tiles; all 8 n-tiles (128 k-outputs) accumulated.
    const int row0 = w * 64;
    #pragma unroll 1
    for (int p = 0; p < 2; ++p) {
        f32x4 C[2][8] = {};   // fp32 accum, fresh per pass
        #pragma unroll 1
        for (int c = 0; c < 4; ++c) {      // K chunks of 32
            short8 Bh[8], Bl[8];
            const int rbase = c * 512 + quad * 16 + col;
            #pragma unroll
            for (int n = 0; n < 8; ++n) {  // prefab B frag, 1KB/wave contiguous
                Bh[n] = uh[rbase + n * 64];
                Bl[n] = ul[rbase + n * 64];
            }
            #pragma unroll
            for (int t = 0; t < 2; ++t) {
                int row = row0 + (p * 2 + t) * 16 + col;
                if (row > SS - 1) row = SS - 1;   // clamp: pad rows read real data
                const float* ap = allm + ((size_t)b * SS + row) * HH + c * 32 + quad * 8;
                short8 Ah, Al;
                split8(ap, Ah, Al);
                #pragma unroll
                for (int n = 0; n < 8; ++n) {
                    C[t][n] = __builtin_amdgcn_mfma_f32_16x16x32_bf16(Ah, Bh[n], C[t][n], 0, 0, 0);
                    C[t][n] = __builtin_amdgcn_mfma_f32_16x16x32_bf16(Ah, Bl[n], C[t][n], 0, 0, 0);
                    C[t][n] = __builtin_amdgcn_mfma_f32_16x16x32_bf16(Al, Bh[n], C[t][n], 0, 0, 0);
                }
            }
        }
        // ---- epilogue in C layout: col=lane&15, row=quad*4+reg ----
        #pragma unroll
        for (int t = 0; t < 2; ++t) {
            float a0 = 0.f, a1 = 0.f, a2 = 0.f, a3 = 0.f;
            #pragma unroll
            for (int n = 0; n < 8; ++n) {
                float lmc = s_lm[n * 16 + col];
                float vrc = s_vr[n * 16 + col];
                a0 = fmaf(vrc, fast_tanh(C[t][n][0] + lmc), a0);
                a1 = fmaf(vrc, fast_tanh(C[t][n][1] + lmc), a1);
                a2 = fmaf(vrc, fast_tanh(C[t][n][2] + lmc), a2);
                a3 = fmaf(vrc, fast_tanh(C[t][n][3] + lmc), a3);
            }
            #pragma unroll
            for (int off = 1; off < 16; off <<= 1) {
                a0 += __shfl_xor(a0, off, 64);
                a1 += __shfl_xor(a1, off, 64);
                a2 += __shfl_xor(a2, off, 64);
                a3 += __shfl_xor(a3, off, 64);
            }
            if (col == 0) {
                int rb = row0 + (p * 2 + t) * 16 + quad * 4;
                s_score[rb + 0] = a0;
                s_score[rb + 1] = a1;
                s_score[rb + 2] = a2;
                s_score[rb + 3] = a3;
            }
        }
    }

    // ---- zero-fill this batch's output row (AFTER mfma loads: stores don't
    //      block the k-loop's vmcnt waits; drained at the next barrier) ----
    {
        float4* orow = reinterpret_cast<float4*>(out + (size_t)b * NI);
        const float4 z4 = make_float4(0.f, 0.f, 0.f, 0.f);
        for (int i = tid; i < NI / 4; i += 256) orow[i] = z4;
    }

    __syncthreads();   // s_score visible; fill stores drained to L2

    // ---- softmax over S ----
    const int s = tid;
    float score = s_score[s] + Vrb[0];
    if (s < SS && mask[b * SS + s]) score = -1e9f;

    float v = (s < SS) ? score : -3.0e38f;
    #pragma unroll
    for (int off = 32; off > 0; off >>= 1)
        v = fmaxf(v, __shfl_down(v, off, 64));
    if (lane == 0) s_red[w] = v;
    __syncthreads();
    float m = fmaxf(fmaxf(s_red[0], s_red[1]), fmaxf(s_red[2], s_red[3]));

    float e = (s < SS) ? __expf(score - m) : 0.f;
    float sv = e;
    #pragma unroll
    for (int off = 32; off > 0; off >>= 1)
        sv += __shfl_down(sv, off, 64);
    if (lane == 0) s_red[4 + w] = sv;
    __syncthreads();
    float tot = (s_red[4] + s_red[5]) + (s_red[6] + s_red[7]);

    // ---- scatter-add (row private to block; in-row duplicate ids -> atomics)
    if (s < SS) {
        float att = e / tot;
        int idx = item_seq[b * SS + s];
        atomicAdd(out + (size_t)b * NI + idx, att);
    }
}

// ---------------------------------------------------------------------------
// Fallback: original fused kernel (used only if ws_size is too small).
// ---------------------------------------------------------------------------
__global__ __launch_bounds__(256, 2)
void rrd_mfma_kernel(const float* __restrict__ allm,      // [B,S,H]
                     const float* __restrict__ lastm,     // [B,H]
                     const int* __restrict__ item_seq,    // [B,S]
                     const unsigned char* __restrict__ mask, // [B,S]
                     const float* __restrict__ Ur,        // [H,H]
                     const float* __restrict__ Wr,        // [H,H]
                     const float* __restrict__ Vr,        // [1,H]
                     const float* __restrict__ Vrb,       // [1]
                     float* __restrict__ out) {           // [B,N]
    const int b = blockIdx.x;
    const int tid = threadIdx.x;
    const int lane = tid & 63;
    const int w = tid >> 6;
    const int col = lane & 15;
    const int quad = lane >> 4;

    __shared__ float s_last[HH];
    __shared__ float s_lm[HH];
    __shared__ float s_vr[HH];
    __shared__ float s_score[256];
    __shared__ float s_red[8];

    if (tid < HH) s_last[tid] = lastm[b * HH + tid];
    else          s_vr[tid - HH] = Vr[tid - HH];
    __syncthreads();

    if (tid < HH) {
        const float4* wrow = reinterpret_cast<const float4*>(Wr + tid * HH);
        const float4* lrow = reinterpret_cast<const float4*>(s_last);
        float4 acc = make_float4(0.f, 0.f, 0.f, 0.f);
        #pragma unroll
        for (int i = 0; i < HH / 4; ++i) {
            float4 wv = wrow[i];
            float4 lv = lrow[i];
            acc.x = fmaf(lv.x, wv.x, acc.x);
            acc.y = fmaf(lv.y, wv.y, acc.y);
            acc.z = fmaf(lv.z, wv.z, acc.z);
            acc.w = fmaf(lv.w, wv.w, acc.w);
        }
        s_lm[tid] = (acc.x + acc.y) + (acc.z + acc.w);
    }
    __syncthreads();

    const int row0 = w * 64;
    #pragma unroll 1
    for (int p = 0; p < 2; ++p) {
        f32x4 C[2][8] = {};
        #pragma unroll 1
        for (int c = 0; c < 4; ++c) {
            short8 Bh[8], Bl[8];
            #pragma unroll
            for (int n = 0; n < 8; ++n) {
                const float* bp = Ur + (size_t)(n * 16 + col) * HH + c * 32 + quad * 8;
                split8(bp, Bh[n], Bl[n]);
            }
            #pragma unroll
            for (int t = 0; t < 2; ++t) {
                int row = row0 + (p * 2 + t) * 16 + col;
                if (row > SS - 1) row = SS - 1;
                const float* ap = allm + ((size_t)b * SS + row) * HH + c * 32 + quad * 8;
                short8 Ah, Al;
                split8(ap, Ah, Al);
                #pragma unroll
                for (int n = 0; n < 8; ++n) {
                    C[t][n] = __builtin_amdgcn_mfma_f32_16x16x32_bf16(Ah, Bh[n], C[t][n], 0, 0, 0);
                    C[t][n] = __builtin_amdgcn_mfma_f32_16x16x32_bf16(Ah, Bl[n], C[t][n], 0, 0, 0);
                    C[t][n] = __builtin_amdgcn_mfma_f32_16x16x32_bf16(Al, Bh[n], C[t][n], 0, 0, 0);
                }
            }
        }
        #pragma unroll
        for (int t = 0; t < 2; ++t) {
            float a0 = 0.f, a1 = 0.f, a2 = 0.f, a3 = 0.f;
            #pragma unroll
            for (int n = 0; n < 8; ++n) {
                float lmc = s_lm[n * 16 + col];
                float vrc = s_vr[n * 16 + col];
                a0 = fmaf(vrc, fast_tanh(C[t][n][0] + lmc), a0);
                a1 = fmaf(vrc, fast_tanh(C[t][n][1] + lmc), a1);
                a2 = fmaf(vrc, fast_tanh(C[t][n][2] + lmc), a2);
                a3 = fmaf(vrc, fast_tanh(C[t][n][3] + lmc), a3);
            }
            #pragma unroll
            for (int off = 1; off < 16; off <<= 1) {
                a0 += __shfl_xor(a0, off, 64);
                a1 += __shfl_xor(a1, off, 64);
                a2 += __shfl_xor(a2, off, 64);
                a3 += __shfl_xor(a3, off, 64);
            }
            if (col == 0) {
                int rb = row0 + (p * 2 + t) * 16 + quad * 4;
                s_score[rb + 0] = a0;
                s_score[rb + 1] = a1;
                s_score[rb + 2] = a2;
                s_score[rb + 3] = a3;
            }
        }
    }

    {
        float4* orow = reinterpret_cast<float4*>(out + (size_t)b * NI);
        const float4 z4 = make_float4(0.f, 0.f, 0.f, 0.f);
        for (int i = tid; i < NI / 4; i += 256) orow[i] = z4;
    }

    __syncthreads();

    const int s = tid;
    float score = s_score[s] + Vrb[0];
    if (s < SS && mask[b * SS + s]) score = -1e9f;

    float v = (s < SS) ? score : -3.0e38f;
    #pragma unroll
    for (int off = 32; off > 0; off >>= 1)
        v = fmaxf(v, __shfl_down(v, off, 64));
    if (lane == 0) s_red[w] = v;
    __syncthreads();
    float m = fmaxf(fmaxf(s_red[0], s_red[1]), fmaxf(s_red[2], s_red[3]));

    float e = (s < SS) ? __expf(score - m) : 0.f;
    float sv = e;
    #pragma unroll
    for (int off = 32; off > 0; off >>= 1)
        sv += __shfl_down(sv, off, 64);
    if (lane == 0) s_red[4 + w] = sv;
    __syncthreads();
    float tot = (s_red[4] + s_red[5]) + (s_red[6] + s_red[7]);

    if (s < SS) {
        float att = e / tot;
        int idx = item_seq[b * SS + s];
        atomicAdd(out + (size_t)b * NI + idx, att);
    }
}

extern "C" void kernel_launch(void* const* d_in, const int* in_sizes, int n_in,
                              void* d_out, int out_size, void* d_ws, size_t ws_size,
                              hipStream_t stream) {
    const float* allm   = (const float*)d_in[0];
    const float* lastm  = (const float*)d_in[1];
    const int*   iseq   = (const int*)d_in[2];
    const unsigned char* mask = (const unsigned char*)d_in[3];
    const float* Ur     = (const float*)d_in[4];
    const float* Wr     = (const float*)d_in[5];
    const float* Vr     = (const float*)d_in[6];
    const float* Vrb    = (const float*)d_in[7];
    float* out          = (float*)d_out;

    const size_t lm_bytes = (size_t)BB * HH * sizeof(float);    // 512 KB
    const size_t ur_bytes = (size_t)HH * HH * sizeof(short);    // 32 KB each
    const size_t need = lm_bytes + 2 * ur_bytes;                // 576 KB

    if (d_ws != nullptr && ws_size >= need) {
        float* lm_ws = (float*)d_ws;
        short* ur_hi = (short*)((char*)d_ws + lm_bytes);
        short* ur_lo = (short*)((char*)d_ws + lm_bytes + ur_bytes);
        rrd_prep_kernel<<<dim3(520), dim3(256), 0, stream>>>(
            lastm, Wr, Ur, lm_ws, ur_hi, ur_lo);
        rrd_mfma_kernel_p<<<dim3(BB), dim3(256), 0, stream>>>(
            allm, iseq, mask, ur_hi, ur_lo, lm_ws, Vr, Vrb, out);
    } else {
        rrd_mfma_kernel<<<dim3(BB), dim3(256), 0, stream>>>(
            allm, lastm, iseq, mask, Ur, Wr, Vr, Vrb, out);
    }
}